// Round 2
// baseline (298.507 us; speedup 1.0000x reference)
//
#include <hip/hip_runtime.h>

// OffsetMSE: min over s in [1,95] of  sum_b sum_{t<L-s} (p[b,t+s]-q[b,t])^2 / (B*(L-s))
// Decomposed: num(s) = (TotPP - HeadPP(s)) + (TotQQ - TailQQ(s)) - 2*C(s)
// C(s) = sum_b sum_t p_pad[t+s]*q[t]  -> 1 FMA/element cross-correlation.

#define LROW   (1 << 20)
#define NBATCH 16
#define TBLK   4096
#define NCHUNK 4
#define CHUNK_T 1024
#define NTHREADS 256
#define PWORDS (TBLK + 96)   // staged p words, global offsets t0+1 .. t0+PWORDS

// +4 words padding per 16 words: keeps 16-aligned runs contiguous & 16B-aligned,
// spreads banks for the strided window reads.
__device__ __forceinline__ int pad16(int i) { return i + (((i) >> 4) << 2); }
#define LDSP_WORDS (PWORDS + ((PWORDS >> 4) << 2))   // 5240

__global__ __launch_bounds__(NTHREADS, 4)
void corr_kernel(const float* __restrict__ P, const float* __restrict__ Q,
                 float* __restrict__ sums) {
    __shared__ float ldsP[LDSP_WORDS];
    __shared__ float red[4][96];
    __shared__ float red2[8];

    const int b    = blockIdx.x >> 8;     // 256 tiles per batch
    const int tile = blockIdx.x & 255;
    const int t0   = tile * TBLK;
    const float* prow = P + (size_t)b * LROW;
    const float* qrow = Q + (size_t)b * LROW;

    const int tid = threadIdx.x;

    // ---- stage p[t0+1 .. t0+PWORDS] into padded LDS (zero beyond row end) ----
    for (int k = tid; k <= PWORDS / 4; k += NTHREADS) {   // k = 0..1048
        const int gbase = t0 + 4 * k;
        float4 v;
        if (gbase + 3 < LROW) {
            v = *reinterpret_cast<const float4*>(prow + gbase);
        } else {
            v.x = (gbase + 0 < LROW) ? prow[gbase + 0] : 0.f;
            v.y = (gbase + 1 < LROW) ? prow[gbase + 1] : 0.f;
            v.z = (gbase + 2 < LROW) ? prow[gbase + 2] : 0.f;
            v.w = (gbase + 3 < LROW) ? prow[gbase + 3] : 0.f;
        }
        float w[4] = {v.x, v.y, v.z, v.w};
        #pragma unroll
        for (int c = 0; c < 4; ++c) {
            const int i = 4 * k - 1 + c;   // lds index: global u = t0+1+i
            if (i >= 0 && i < PWORDS) ldsP[pad16(i)] = w[c];
        }
    }
    __syncthreads();

    const int tg    = tid >> 2;       // 0..63 t-groups (16 consecutive t each)
    const int cls   = tid & 3;        // s-class: s in [1+24*cls, 24+24*cls]
    const int sbase = 24 * cls;

    float acc[24];
    #pragma unroll
    for (int j = 0; j < 24; ++j) acc[j] = 0.f;
    float pp = 0.f, qq = 0.f;

    for (int cc = 0; cc < NCHUNK; ++cc) {
        const int tloc = cc * CHUNK_T + tg * 16;

        // q -> regs (also feeds TotQQ); p same-range re-read feeds TotPP
        float qr[16];
        const float* qp = qrow + t0 + tloc;
        #pragma unroll
        for (int k = 0; k < 4; ++k) {
            float4 v = *reinterpret_cast<const float4*>(qp + 4 * k);
            qr[4*k+0] = v.x; qr[4*k+1] = v.y; qr[4*k+2] = v.z; qr[4*k+3] = v.w;
        }
        #pragma unroll
        for (int r = 0; r < 16; ++r) qq = fmaf(qr[r], qr[r], qq);

        const float* pg = prow + t0 + tloc;
        #pragma unroll
        for (int k = 0; k < 4; ++k) {
            float4 v = *reinterpret_cast<const float4*>(pg + 4 * k);
            pp = fmaf(v.x, v.x, pp); pp = fmaf(v.y, v.y, pp);
            pp = fmaf(v.z, v.z, pp); pp = fmaf(v.w, v.w, pp);
        }

        // ---- sliding register window over LDS p ----
        const int base = tloc + sbase;            // multiple of 4
        float W[8][4];
        #pragma unroll
        for (int k = 0; k < 5; ++k)
            *reinterpret_cast<float4*>(W[k]) =
                *reinterpret_cast<const float4*>(&ldsP[pad16(base + 4 * k)]);

        #pragma unroll
        for (int J = 0; J < 6; ++J) {
            if (J < 5) {
                const int i = base + 4 * J + 20;
                *reinterpret_cast<float4*>(W[(J + 5) & 7]) =
                    *reinterpret_cast<const float4*>(&ldsP[pad16(i)]);
            }
            #pragma unroll
            for (int d = 0; d < 4; ++d) {
                const int j = 4 * J + d;          // shift s = 1 + sbase + j
                float a = acc[j];
                #pragma unroll
                for (int r = 0; r < 16; ++r) {
                    const int widx = d + r;       // word = base + 4J + widx
                    const float pv = W[(J + (widx >> 2)) & 7][widx & 3];
                    a = fmaf(pv, qr[r], a);
                }
                acc[j] = a;
            }
        }
    }

    // ---- reduction: butterfly over same-class lanes (xor 4,8,16,32) ----
    #pragma unroll
    for (int j = 0; j < 24; ++j) {
        float v = acc[j];
        v += __shfl_xor(v, 4);
        v += __shfl_xor(v, 8);
        v += __shfl_xor(v, 16);
        v += __shfl_xor(v, 32);
        acc[j] = v;
    }
    #pragma unroll
    for (int m = 1; m <= 32; m <<= 1) {
        pp += __shfl_xor(pp, m);
        qq += __shfl_xor(qq, m);
    }

    const int wave = tid >> 6;
    const int lane = tid & 63;
    if (lane < 4) {
        #pragma unroll
        for (int j = 0; j < 24; ++j) red[wave][lane * 24 + j] = acc[j];
    }
    if (lane == 0) { red2[wave] = pp; red2[4 + wave] = qq; }
    __syncthreads();

    if (tid < 96) {
        const float v = red[0][tid] + red[1][tid] + red[2][tid] + red[3][tid];
        atomicAdd(&sums[1 + tid], v);            // index = s (1..96); 96 unused
    } else if (tid == 96) {
        // every t covered by 4 class-threads -> scale 0.25
        atomicAdd(&sums[97], 0.25f * (red2[0] + red2[1] + red2[2] + red2[3]));
    } else if (tid == 97) {
        atomicAdd(&sums[98], 0.25f * (red2[4] + red2[5] + red2[6] + red2[7]));
    }
}

__global__ void minloss_kernel(const float* __restrict__ P, const float* __restrict__ Q,
                               const float* __restrict__ sums, float* __restrict__ out) {
    __shared__ float hp[96], tq[96], lossbuf[96];
    const int tid = threadIdx.x;   // 128 threads
    if (tid < 95) {
        float s1 = 0.f, s2 = 0.f;
        for (int b = 0; b < NBATCH; ++b) {
            const float pv = P[(size_t)b * LROW + tid];
            s1 = fmaf(pv, pv, s1);
            const float qv = Q[(size_t)b * LROW + (LROW - 1 - tid)];
            s2 = fmaf(qv, qv, s2);
        }
        hp[tid] = s1;      // sum_b p[u=tid]^2
        tq[tid] = s2;      // sum_b q[L-1-tid]^2
    }
    __syncthreads();
    if (tid >= 1 && tid <= 95) {
        const int s = tid;
        float head = 0.f, tail = 0.f;
        for (int u = 0; u < s; ++u) { head += hp[u]; tail += tq[u]; }
        const float totpp = sums[97], totqq = sums[98];
        const float num = (totpp - head) + (totqq - tail) - 2.f * sums[s];
        lossbuf[s] = num / (16.f * (float)(LROW - s));
    }
    __syncthreads();
    if (tid == 0) {
        float m = lossbuf[1];
        for (int s = 2; s <= 95; ++s) m = fminf(m, lossbuf[s]);
        out[0] = m;
    }
}

extern "C" void kernel_launch(void* const* d_in, const int* in_sizes, int n_in,
                              void* d_out, int out_size, void* d_ws, size_t ws_size,
                              hipStream_t stream) {
    const float* P = (const float*)d_in[0];   // predict
    const float* Q = (const float*)d_in[1];   // target
    float* sums = (float*)d_ws;               // [0..96]=C(s), [97]=TotPP, [98]=TotQQ

    hipMemsetAsync(d_ws, 0, 128 * sizeof(float), stream);
    corr_kernel<<<NBATCH * (LROW / TBLK), NTHREADS, 0, stream>>>(P, Q, sums);
    minloss_kernel<<<1, 128, 0, stream>>>(P, Q, sums, (float*)d_out);
}